// Round 4
// baseline (411.714 us; speedup 1.0000x reference)
//
#include <hip/hip_runtime.h>

// Problem constants (from reference)
#define N_RAYS   16384
#define N_SAMP   256
#define GRID_N   160
#define GRID_VOX (GRID_N * GRID_N * GRID_N)   // 4,096,000
#define GB       80                            // 2x2x2 blocks per axis
#define NBLK     (GB * GB * GB)                // 512,000 blocks per copy
#define COPY_VOX (NBLK * 8)                    // 4,096,000 voxels per copy

typedef unsigned int u32x4 __attribute__((ext_vector_type(4)));

__device__ __constant__ float kXyzMin   = -1.2f;
__device__ __constant__ float kScale    = 159.0f / 2.4f;          // 66.25
__device__ __constant__ float kActShift = -9.21024036697530f;     // log(1/(1-1e-4)-1)
__device__ __constant__ float kInterval = 0.01f;

__device__ __forceinline__ float sigmoidf_(float x) {
    return 1.0f / (1.0f + expf(-x));
}

// f32 -> bf16 bits, round-nearest-even
__device__ __forceinline__ unsigned int f2bf(float f) {
    unsigned int u = __float_as_uint(f);
    return (u + 0x7fffu + ((u >> 16) & 1u)) >> 16;
}
__device__ __forceinline__ float bf_lo(unsigned int u) {
    return __uint_as_float(u << 16);
}
__device__ __forceinline__ float bf_hi(unsigned int u) {
    return __uint_as_float(u & 0xffff0000u);
}

// ---------------------------------------------------------------------------
// Repack planar f32 {density, k0.rgb} into parity-replicated bf16 2x2x2-block
// grid, x-FASTEST block order:  blk = (yb*80 + zb)*80 + xb.
// Copy c: YP==2 -> c = py*2+pz (4 copies); YP==1 -> c = pz (2 copies).
// One thread per z-pair (= one float4/uint4 = 2 voxels):
//   within-copy pair index = blk*4 + sx*2 + sy,  thread linear i maps with
//   p = i&3 (sx=p>>1, sy=p&1), xb fastest -> 16B writes fully coalesced.
// uint4 = { d0|r0<<16, g0|b0<<16, d1|r1<<16, g1|b1<<16 }  (z0 voxel, z1 voxel)
// ---------------------------------------------------------------------------
template<int YP>
__global__ __launch_bounds__(256)
void repack_kernel(const float* __restrict__ dgrid,
                   const float* __restrict__ kgrid,
                   u32x4* __restrict__ out)
{
    const int i = blockIdx.x * 256 + threadIdx.x;   // grid sized exactly
    const int p  = i & 3;
    const int sx = p >> 1, sy = p & 1;
    int t = i >> 2;
    const int xb = t % GB; t /= GB;
    const int zb = t % GB; t /= GB;
    const int yb = t % GB; const int c = t / GB;
    const int py = (YP == 2) ? (c >> 1) : 0;
    const int pz = (YP == 2) ? (c & 1)  : c;

    const int x  = xb * 2 + sx;                        // <= 159 always
    const int y  = min(py + yb * 2 + sy, GRID_N - 1);  // pad dup-clamped
    const int zs = pz + zb * 2;
    const int z0 = min(zs,     GRID_N - 1);
    const int z1 = min(zs + 1, GRID_N - 1);

    const int g0 = (x * GRID_N + y) * GRID_N + z0;
    const int g1 = (x * GRID_N + y) * GRID_N + z1;

    const unsigned int d0 = f2bf(dgrid[g0]);
    const unsigned int r0 = f2bf(kgrid[g0]);
    const unsigned int gg0 = f2bf(kgrid[g0 + GRID_VOX]);
    const unsigned int b0 = f2bf(kgrid[g0 + 2 * GRID_VOX]);
    const unsigned int d1 = f2bf(dgrid[g1]);
    const unsigned int r1 = f2bf(kgrid[g1]);
    const unsigned int gg1 = f2bf(kgrid[g1 + GRID_VOX]);
    const unsigned int b1 = f2bf(kgrid[g1 + 2 * GRID_VOX]);

    u32x4 o;
    o.x = d0 | (r0 << 16);
    o.y = gg0 | (b0 << 16);
    o.z = d1 | (r1 << 16);
    o.w = gg1 | (b1 << 16);
    __builtin_nontemporal_store(o, &out[i]);
}

// ---------------------------------------------------------------------------
// Render over the replicated block grid (x-fastest block order).
// YP==2: copy (y0&1, z0&1); the 4 needed float4s are contiguous [a0..a0+3].
// YP==1: copy (z0&1); 4 separate float4s (x,y straddle across blocks).
// ---------------------------------------------------------------------------
template<int YP>
__global__ __launch_bounds__(256)
void render_blk_kernel(const float* __restrict__ ray_pts,  // [N_RAYS, N_SAMP, 3]
                       const float4* __restrict__ P,       // packed copies
                       float* __restrict__ out_rgb,        // [N_RAYS, 3]
                       float* __restrict__ out_w,          // [N_RAYS, N_SAMP]
                       float* __restrict__ out_ainv)       // [N_RAYS]
{
    const int r    = blockIdx.x;
    const int s    = threadIdx.x;
    const int lane = s & 63;
    const int wid  = s >> 6;

    __shared__ float s_wtot[4];
    __shared__ float s_rgb[4][3];

    const float* rp = ray_pts + ((size_t)r * N_SAMP + s) * 3;
    const float px  = __builtin_nontemporal_load(&rp[0]);
    const float py_ = __builtin_nontemporal_load(&rp[1]);
    const float pz_ = __builtin_nontemporal_load(&rp[2]);

    float ux = fminf(fmaxf((px  - kXyzMin) * kScale, 0.0f), 159.0f);
    float uy = fminf(fmaxf((py_ - kXyzMin) * kScale, 0.0f), 159.0f);
    float uz = fminf(fmaxf((pz_ - kXyzMin) * kScale, 0.0f), 159.0f);
    int x0 = min((int)floorf(ux), GRID_N - 2);   // boundary: fx becomes 1.0
    int y0 = min((int)floorf(uy), GRID_N - 2);
    int z0 = min((int)floorf(uz), GRID_N - 2);
    const float fx = ux - (float)x0, fy = uy - (float)y0, fz = uz - (float)z0;
    const float gx = 1.0f - fx, gy = 1.0f - fy, gz = 1.0f - fz;

    const int zp = z0 & 1, zb = z0 >> 1;

    // q00=(x0,y0) q01=(x0,y1) q10=(x1,y0) q11=(x1,y1); each float4 = z-pair
    float4 q00, q01, q10, q11;
    if (YP == 2) {
        const int yp = y0 & 1, yb = y0 >> 1;
        const int xb = x0 >> 1, sx = x0 & 1;
        const float4* B = P + (size_t)(yp * 2 + zp) * (NBLK * 4);
        const int a0 = ((yb * GB + zb) * GB + xb) * 4 + sx * 2;
        // contiguous 64B: works for sx=0 (same block) and sx=1 (next block,
        // adjacent in x-fastest order; x0<=158 so xb+1<=79)
        q00 = B[a0];     q01 = B[a0 + 1];
        q10 = B[a0 + 2]; q11 = B[a0 + 3];
    } else {
        const int y1 = y0 + 1, x1 = x0 + 1;
        const float4* B = P + (size_t)zp * (NBLK * 4);
        #define ADDR(X, Y) \
            ((((Y >> 1) * GB + zb) * GB + (X >> 1)) * 4 + (X & 1) * 2 + (Y & 1))
        q00 = B[ADDR(x0, y0)]; q01 = B[ADDR(x0, y1)];
        q10 = B[ADDR(x1, y0)]; q11 = B[ADDR(x1, y1)];
        #undef ADDR
    }

    float d = 0.f, kr = 0.f, kg = 0.f, kb = 0.f;
    {
        // each float4: (.x,.y) = voxel at z0, (.z,.w) = voxel at z1
        const float wxy00 = gx * gy, wxy01 = gx * fy;
        const float wxy10 = fx * gy, wxy11 = fx * fy;
        #define ACC(Q, WXY)                                               \
        {                                                                 \
            const unsigned a0_ = __float_as_uint((Q).x);                  \
            const unsigned b0_ = __float_as_uint((Q).y);                  \
            const unsigned a1_ = __float_as_uint((Q).z);                  \
            const unsigned b1_ = __float_as_uint((Q).w);                  \
            const float w0_ = (WXY) * gz, w1_ = (WXY) * fz;               \
            d  += w0_ * bf_lo(a0_) + w1_ * bf_lo(a1_);                    \
            kr += w0_ * bf_hi(a0_) + w1_ * bf_hi(a1_);                    \
            kg += w0_ * bf_lo(b0_) + w1_ * bf_lo(b1_);                    \
            kb += w0_ * bf_hi(b0_) + w1_ * bf_hi(b1_);                    \
        }
        ACC(q00, wxy00); ACC(q01, wxy01); ACC(q10, wxy10); ACC(q11, wxy11);
        #undef ACC
    }

    // alpha = 1 - (1 + exp(d + shift))^(-interval)
    const float e     = expf(d + kActShift);
    const float sp    = log1pf(e);               // softplus; inf-safe
    const float om    = expf(-kInterval * sp);   // (1 - alpha)
    const float alpha = 1.0f - om;

    // exclusive cumprod of (1-alpha) across 256 samples
    float v = om;
    #pragma unroll
    for (int off = 1; off < 64; off <<= 1) {
        float o = __shfl_up(v, off, 64);
        if (lane >= off) v *= o;
    }
    if (lane == 63) s_wtot[wid] = v;
    __syncthreads();
    float wpref = 1.0f;
    #pragma unroll
    for (int w = 0; w < 4; ++w)
        if (w < wid) wpref *= s_wtot[w];
    const float total = s_wtot[0] * s_wtot[1] * s_wtot[2] * s_wtot[3];

    float excl = __shfl_up(v, 1, 64);
    if (lane == 0) excl = 1.0f;
    const float T  = wpref * excl;
    const float ws = T * alpha;

    __builtin_nontemporal_store(ws, &out_w[(size_t)r * N_SAMP + s]);

    float contrib[3];
    contrib[0] = ws * sigmoidf_(kr);
    contrib[1] = ws * sigmoidf_(kg);
    contrib[2] = ws * sigmoidf_(kb);

    #pragma unroll
    for (int c = 0; c < 3; ++c) {
        float x = contrib[c];
        #pragma unroll
        for (int off = 32; off >= 1; off >>= 1)
            x += __shfl_xor(x, off, 64);
        if (lane == 0) s_rgb[wid][c] = x;
    }
    __syncthreads();

    if (s == 0) {
        #pragma unroll
        for (int c = 0; c < 3; ++c) {
            float acc = s_rgb[0][c] + s_rgb[1][c] + s_rgb[2][c] + s_rgb[3][c];
            out_rgb[r * 3 + c] = acc + total;   // + alphainv_last
        }
        out_ainv[r] = total;
    }
}

// ---------------------------------------------------------------------------
// Last-resort fallback (round-1 planar kernel) if ws is tiny.
// ---------------------------------------------------------------------------
__global__ __launch_bounds__(256)
void render_kernel(const float* __restrict__ ray_pts,
                   const float* __restrict__ dgrid,
                   const float* __restrict__ kgrid,
                   float* __restrict__ out_rgb,
                   float* __restrict__ out_w,
                   float* __restrict__ out_ainv)
{
    const int r    = blockIdx.x;
    const int s    = threadIdx.x;
    const int lane = s & 63;
    const int wid  = s >> 6;

    __shared__ float s_wtot[4];
    __shared__ float s_rgb[4][3];

    const float* rp = ray_pts + ((size_t)r * N_SAMP + s) * 3;
    const float px = rp[0], py = rp[1], pz = rp[2];

    float ux = fminf(fmaxf((px - kXyzMin) * kScale, 0.0f), 159.0f);
    float uy = fminf(fmaxf((py - kXyzMin) * kScale, 0.0f), 159.0f);
    float uz = fminf(fmaxf((pz - kXyzMin) * kScale, 0.0f), 159.0f);
    int x0 = (int)floorf(ux), y0 = (int)floorf(uy), z0 = (int)floorf(uz);
    int x1 = min(x0 + 1, 159), y1 = min(y0 + 1, 159), z1 = min(z0 + 1, 159);
    float fx = ux - (float)x0, fy = uy - (float)y0, fz = uz - (float)z0;
    float gx = 1.0f - fx, gy = 1.0f - fy, gz = 1.0f - fz;

    const int o00 = (x0 * GRID_N + y0) * GRID_N;
    const int o01 = (x0 * GRID_N + y1) * GRID_N;
    const int o10 = (x1 * GRID_N + y0) * GRID_N;
    const int o11 = (x1 * GRID_N + y1) * GRID_N;

    const float w000 = gx * gy * gz, w001 = gx * gy * fz;
    const float w010 = gx * fy * gz, w011 = gx * fy * fz;
    const float w100 = fx * gy * gz, w101 = fx * gy * fz;
    const float w110 = fx * fy * gz, w111 = fx * fy * fz;

    float d =
        dgrid[o00 + z0] * w000 + dgrid[o00 + z1] * w001 +
        dgrid[o01 + z0] * w010 + dgrid[o01 + z1] * w011 +
        dgrid[o10 + z0] * w100 + dgrid[o10 + z1] * w101 +
        dgrid[o11 + z0] * w110 + dgrid[o11 + z1] * w111;

    const float e   = expf(d + kActShift);
    const float sp  = log1pf(e);
    const float om  = expf(-kInterval * sp);
    const float alpha = 1.0f - om;

    float v = om;
    #pragma unroll
    for (int off = 1; off < 64; off <<= 1) {
        float o = __shfl_up(v, off, 64);
        if (lane >= off) v *= o;
    }
    if (lane == 63) s_wtot[wid] = v;
    __syncthreads();
    float wpref = 1.0f;
    #pragma unroll
    for (int w = 0; w < 4; ++w)
        if (w < wid) wpref *= s_wtot[w];
    const float total = s_wtot[0] * s_wtot[1] * s_wtot[2] * s_wtot[3];

    float excl = __shfl_up(v, 1, 64);
    if (lane == 0) excl = 1.0f;
    const float T  = wpref * excl;
    const float ws = T * alpha;

    out_w[(size_t)r * N_SAMP + s] = ws;

    float contrib[3];
    #pragma unroll
    for (int c = 0; c < 3; ++c) {
        const float* g = kgrid + (size_t)c * GRID_VOX;
        float k =
            g[o00 + z0] * w000 + g[o00 + z1] * w001 +
            g[o01 + z0] * w010 + g[o01 + z1] * w011 +
            g[o10 + z0] * w100 + g[o10 + z1] * w101 +
            g[o11 + z0] * w110 + g[o11 + z1] * w111;
        contrib[c] = ws * sigmoidf_(k);
    }

    #pragma unroll
    for (int c = 0; c < 3; ++c) {
        float x = contrib[c];
        #pragma unroll
        for (int off = 32; off >= 1; off >>= 1)
            x += __shfl_xor(x, off, 64);
        if (lane == 0) s_rgb[wid][c] = x;
    }
    __syncthreads();

    if (s == 0) {
        #pragma unroll
        for (int c = 0; c < 3; ++c) {
            float acc = s_rgb[0][c] + s_rgb[1][c] + s_rgb[2][c] + s_rgb[3][c];
            out_rgb[r * 3 + c] = acc + total;
        }
        out_ainv[r] = total;
    }
}

extern "C" void kernel_launch(void* const* d_in, const int* in_sizes, int n_in,
                              void* d_out, int out_size, void* d_ws, size_t ws_size,
                              hipStream_t stream) {
    const float* ray_pts = (const float*)d_in[0];
    const float* dgrid   = (const float*)d_in[1];
    const float* kgrid   = (const float*)d_in[2];

    float* out_rgb  = (float*)d_out;                       // 16384*3
    float* out_w    = out_rgb + (size_t)N_RAYS * 3;        // 16384*256
    float* out_ainv = out_w + (size_t)N_RAYS * N_SAMP;     // 16384

    const size_t bytes_per_copy = (size_t)COPY_VOX * 8;    // 32,768,000
    const size_t need4 = 4 * bytes_per_copy;               // 131 MB
    const size_t need2 = 2 * bytes_per_copy;               // 65.5 MB

    if (ws_size >= need4) {
        const int pairs = 4 * NBLK * 4;                    // 8,192,000
        repack_kernel<2><<<pairs / 256, 256, 0, stream>>>(dgrid, kgrid, (u32x4*)d_ws);
        render_blk_kernel<2><<<N_RAYS, N_SAMP, 0, stream>>>(
            ray_pts, (const float4*)d_ws, out_rgb, out_w, out_ainv);
    } else if (ws_size >= need2) {
        const int pairs = 2 * NBLK * 4;                    // 4,096,000
        repack_kernel<1><<<pairs / 256, 256, 0, stream>>>(dgrid, kgrid, (u32x4*)d_ws);
        render_blk_kernel<1><<<N_RAYS, N_SAMP, 0, stream>>>(
            ray_pts, (const float4*)d_ws, out_rgb, out_w, out_ainv);
    } else {
        render_kernel<<<N_RAYS, N_SAMP, 0, stream>>>(
            ray_pts, dgrid, kgrid, out_rgb, out_w, out_ainv);
    }
}

// Round 5
// 168.674 us; speedup vs baseline: 2.4409x; 2.4409x over previous
//
#include <hip/hip_runtime.h>

// Problem constants (from reference)
#define N_RAYS   16384
#define N_SAMP   256
#define GRID_N   160
#define GRID_VOX (GRID_N * GRID_N * GRID_N)   // 4,096,000
#define GB       80                            // 2x2x2 blocks per axis
#define NBLK     (GB * GB * GB)                // 512,000 blocks per copy
#define COPY_VOX (NBLK * 8)                    // 4,096,000 voxels per copy

typedef unsigned int u32x4 __attribute__((ext_vector_type(4)));

__device__ __constant__ float kXyzMin   = -1.2f;
__device__ __constant__ float kScale    = 159.0f / 2.4f;          // 66.25
__device__ __constant__ float kActShift = -9.21024036697530f;     // log(1/(1-1e-4)-1)
__device__ __constant__ float kInterval = 0.01f;

__device__ __forceinline__ float sigmoidf_(float x) {
    return 1.0f / (1.0f + expf(-x));
}

// f32 -> bf16 bits, round-nearest-even
__device__ __forceinline__ unsigned int f2bf(float f) {
    unsigned int u = __float_as_uint(f);
    return (u + 0x7fffu + ((u >> 16) & 1u)) >> 16;
}
__device__ __forceinline__ float bf_lo(unsigned int u) {
    return __uint_as_float(u << 16);
}
__device__ __forceinline__ float bf_hi(unsigned int u) {
    return __uint_as_float(u & 0xffff0000u);
}

// ---------------------------------------------------------------------------
// Repack planar f32 {density, k0.rgb} into parity-replicated bf16 2x2x2-block
// grid, x-FASTEST block order in memory:  blk = (yb*80 + zb)*80 + xb,
// pair index within copy = blk*4 + sx*2 + sy (pair = z0,z1 voxels = 16B).
//
// THREAD order is zb-fastest (NOT the memory order):
//   i -> p=i&3 (sx=p>>1, sy=p&1), t=i>>2: zb fastest, then xb, yb, copy.
// Reads: a 4-lane quad covers the 4 (x,y) parity rows at one z-pair; the 16
// quads of a wave advance zb -> each source row is read as 128B contiguous
// (full-line consumption). Writes: each quad emits one full 64B output line
// (4 float4s), quads scattered at 5120B stride — full-line writes, no RMW.
// uint4 = { d0|r0<<16, g0|b0<<16, d1|r1<<16, g1|b1<<16 }  (z0 voxel, z1 voxel)
// ---------------------------------------------------------------------------
template<int YP>
__global__ __launch_bounds__(256)
void repack_kernel(const float* __restrict__ dgrid,
                   const float* __restrict__ kgrid,
                   u32x4* __restrict__ out)
{
    const int i = blockIdx.x * 256 + threadIdx.x;   // grid sized exactly
    const int p  = i & 3;
    const int sx = p >> 1, sy = p & 1;
    int t = i >> 2;
    const int zb = t % GB; t /= GB;
    const int xb = t % GB; t /= GB;
    const int yb = t % GB; const int c = t / GB;
    const int py = (YP == 2) ? (c >> 1) : 0;
    const int pz = (YP == 2) ? (c & 1)  : c;

    const int x  = xb * 2 + sx;                        // <= 159 always
    const int y  = min(py + yb * 2 + sy, GRID_N - 1);  // pad dup-clamped
    const int zs = pz + zb * 2;
    const int z0 = min(zs,     GRID_N - 1);
    const int z1 = min(zs + 1, GRID_N - 1);

    const int g0 = (x * GRID_N + y) * GRID_N + z0;
    const int g1 = (x * GRID_N + y) * GRID_N + z1;

    const unsigned int d0  = f2bf(dgrid[g0]);
    const unsigned int r0  = f2bf(kgrid[g0]);
    const unsigned int gg0 = f2bf(kgrid[g0 + GRID_VOX]);
    const unsigned int b0  = f2bf(kgrid[g0 + 2 * GRID_VOX]);
    const unsigned int d1  = f2bf(dgrid[g1]);
    const unsigned int r1  = f2bf(kgrid[g1]);
    const unsigned int gg1 = f2bf(kgrid[g1 + GRID_VOX]);
    const unsigned int b1  = f2bf(kgrid[g1 + 2 * GRID_VOX]);

    u32x4 o;
    o.x = d0  | (r0 << 16);
    o.y = gg0 | (b0 << 16);
    o.z = d1  | (r1 << 16);
    o.w = gg1 | (b1 << 16);

    // explicit x-fastest output address
    const size_t a = (size_t)c * (NBLK * 4)
                   + (size_t)(((yb * GB + zb) * GB + xb) << 2) + p;
    __builtin_nontemporal_store(o, &out[a]);
}

// ---------------------------------------------------------------------------
// Render over the replicated block grid (x-fastest block order).
// YP==2: copy (y0&1, z0&1); the 4 needed float4s are contiguous [a0..a0+3].
// YP==1: copy (z0&1); 4 separate float4s (x,y straddle across blocks).
// ---------------------------------------------------------------------------
template<int YP>
__global__ __launch_bounds__(256)
void render_blk_kernel(const float* __restrict__ ray_pts,  // [N_RAYS, N_SAMP, 3]
                       const float4* __restrict__ P,       // packed copies
                       float* __restrict__ out_rgb,        // [N_RAYS, 3]
                       float* __restrict__ out_w,          // [N_RAYS, N_SAMP]
                       float* __restrict__ out_ainv)       // [N_RAYS]
{
    const int r    = blockIdx.x;
    const int s    = threadIdx.x;
    const int lane = s & 63;
    const int wid  = s >> 6;

    __shared__ float s_wtot[4];
    __shared__ float s_rgb[4][3];

    const float* rp = ray_pts + ((size_t)r * N_SAMP + s) * 3;
    const float px  = __builtin_nontemporal_load(&rp[0]);
    const float py_ = __builtin_nontemporal_load(&rp[1]);
    const float pz_ = __builtin_nontemporal_load(&rp[2]);

    float ux = fminf(fmaxf((px  - kXyzMin) * kScale, 0.0f), 159.0f);
    float uy = fminf(fmaxf((py_ - kXyzMin) * kScale, 0.0f), 159.0f);
    float uz = fminf(fmaxf((pz_ - kXyzMin) * kScale, 0.0f), 159.0f);
    int x0 = min((int)floorf(ux), GRID_N - 2);   // boundary: fx becomes 1.0
    int y0 = min((int)floorf(uy), GRID_N - 2);
    int z0 = min((int)floorf(uz), GRID_N - 2);
    const float fx = ux - (float)x0, fy = uy - (float)y0, fz = uz - (float)z0;
    const float gx = 1.0f - fx, gy = 1.0f - fy, gz = 1.0f - fz;

    const int zp = z0 & 1, zb = z0 >> 1;

    // q00=(x0,y0) q01=(x0,y1) q10=(x1,y0) q11=(x1,y1); each float4 = z-pair
    float4 q00, q01, q10, q11;
    if (YP == 2) {
        const int yp = y0 & 1, yb = y0 >> 1;
        const int xb = x0 >> 1, sx = x0 & 1;
        const float4* B = P + (size_t)(yp * 2 + zp) * (NBLK * 4);
        const int a0 = ((yb * GB + zb) * GB + xb) * 4 + sx * 2;
        // contiguous 64B: works for sx=0 (same block) and sx=1 (next block,
        // adjacent in x-fastest order; x0<=158 so xb+1<=79)
        q00 = B[a0];     q01 = B[a0 + 1];
        q10 = B[a0 + 2]; q11 = B[a0 + 3];
    } else {
        const int y1 = y0 + 1, x1 = x0 + 1;
        const float4* B = P + (size_t)zp * (NBLK * 4);
        #define ADDR(X, Y) \
            ((((Y >> 1) * GB + zb) * GB + (X >> 1)) * 4 + (X & 1) * 2 + (Y & 1))
        q00 = B[ADDR(x0, y0)]; q01 = B[ADDR(x0, y1)];
        q10 = B[ADDR(x1, y0)]; q11 = B[ADDR(x1, y1)];
        #undef ADDR
    }

    float d = 0.f, kr = 0.f, kg = 0.f, kb = 0.f;
    {
        // each float4: (.x,.y) = voxel at z0, (.z,.w) = voxel at z1
        const float wxy00 = gx * gy, wxy01 = gx * fy;
        const float wxy10 = fx * gy, wxy11 = fx * fy;
        #define ACC(Q, WXY)                                               \
        {                                                                 \
            const unsigned a0_ = __float_as_uint((Q).x);                  \
            const unsigned b0_ = __float_as_uint((Q).y);                  \
            const unsigned a1_ = __float_as_uint((Q).z);                  \
            const unsigned b1_ = __float_as_uint((Q).w);                  \
            const float w0_ = (WXY) * gz, w1_ = (WXY) * fz;               \
            d  += w0_ * bf_lo(a0_) + w1_ * bf_lo(a1_);                    \
            kr += w0_ * bf_hi(a0_) + w1_ * bf_hi(a1_);                    \
            kg += w0_ * bf_lo(b0_) + w1_ * bf_lo(b1_);                    \
            kb += w0_ * bf_hi(b0_) + w1_ * bf_hi(b1_);                    \
        }
        ACC(q00, wxy00); ACC(q01, wxy01); ACC(q10, wxy10); ACC(q11, wxy11);
        #undef ACC
    }

    // alpha = 1 - (1 + exp(d + shift))^(-interval)
    const float e     = expf(d + kActShift);
    const float sp    = log1pf(e);               // softplus; inf-safe
    const float om    = expf(-kInterval * sp);   // (1 - alpha)
    const float alpha = 1.0f - om;

    // exclusive cumprod of (1-alpha) across 256 samples
    float v = om;
    #pragma unroll
    for (int off = 1; off < 64; off <<= 1) {
        float o = __shfl_up(v, off, 64);
        if (lane >= off) v *= o;
    }
    if (lane == 63) s_wtot[wid] = v;
    __syncthreads();
    float wpref = 1.0f;
    #pragma unroll
    for (int w = 0; w < 4; ++w)
        if (w < wid) wpref *= s_wtot[w];
    const float total = s_wtot[0] * s_wtot[1] * s_wtot[2] * s_wtot[3];

    float excl = __shfl_up(v, 1, 64);
    if (lane == 0) excl = 1.0f;
    const float T  = wpref * excl;
    const float ws = T * alpha;

    __builtin_nontemporal_store(ws, &out_w[(size_t)r * N_SAMP + s]);

    float contrib[3];
    contrib[0] = ws * sigmoidf_(kr);
    contrib[1] = ws * sigmoidf_(kg);
    contrib[2] = ws * sigmoidf_(kb);

    #pragma unroll
    for (int c = 0; c < 3; ++c) {
        float x = contrib[c];
        #pragma unroll
        for (int off = 32; off >= 1; off >>= 1)
            x += __shfl_xor(x, off, 64);
        if (lane == 0) s_rgb[wid][c] = x;
    }
    __syncthreads();

    if (s == 0) {
        #pragma unroll
        for (int c = 0; c < 3; ++c) {
            float acc = s_rgb[0][c] + s_rgb[1][c] + s_rgb[2][c] + s_rgb[3][c];
            out_rgb[r * 3 + c] = acc + total;   // + alphainv_last
        }
        out_ainv[r] = total;
    }
}

// ---------------------------------------------------------------------------
// Last-resort fallback (round-1 planar kernel) if ws is tiny.
// ---------------------------------------------------------------------------
__global__ __launch_bounds__(256)
void render_kernel(const float* __restrict__ ray_pts,
                   const float* __restrict__ dgrid,
                   const float* __restrict__ kgrid,
                   float* __restrict__ out_rgb,
                   float* __restrict__ out_w,
                   float* __restrict__ out_ainv)
{
    const int r    = blockIdx.x;
    const int s    = threadIdx.x;
    const int lane = s & 63;
    const int wid  = s >> 6;

    __shared__ float s_wtot[4];
    __shared__ float s_rgb[4][3];

    const float* rp = ray_pts + ((size_t)r * N_SAMP + s) * 3;
    const float px = rp[0], py = rp[1], pz = rp[2];

    float ux = fminf(fmaxf((px - kXyzMin) * kScale, 0.0f), 159.0f);
    float uy = fminf(fmaxf((py - kXyzMin) * kScale, 0.0f), 159.0f);
    float uz = fminf(fmaxf((pz - kXyzMin) * kScale, 0.0f), 159.0f);
    int x0 = (int)floorf(ux), y0 = (int)floorf(uy), z0 = (int)floorf(uz);
    int x1 = min(x0 + 1, 159), y1 = min(y0 + 1, 159), z1 = min(z0 + 1, 159);
    float fx = ux - (float)x0, fy = uy - (float)y0, fz = uz - (float)z0;
    float gx = 1.0f - fx, gy = 1.0f - fy, gz = 1.0f - fz;

    const int o00 = (x0 * GRID_N + y0) * GRID_N;
    const int o01 = (x0 * GRID_N + y1) * GRID_N;
    const int o10 = (x1 * GRID_N + y0) * GRID_N;
    const int o11 = (x1 * GRID_N + y1) * GRID_N;

    const float w000 = gx * gy * gz, w001 = gx * gy * fz;
    const float w010 = gx * fy * gz, w011 = gx * fy * fz;
    const float w100 = fx * gy * gz, w101 = fx * gy * fz;
    const float w110 = fx * fy * gz, w111 = fx * fy * fz;

    float d =
        dgrid[o00 + z0] * w000 + dgrid[o00 + z1] * w001 +
        dgrid[o01 + z0] * w010 + dgrid[o01 + z1] * w011 +
        dgrid[o10 + z0] * w100 + dgrid[o10 + z1] * w101 +
        dgrid[o11 + z0] * w110 + dgrid[o11 + z1] * w111;

    const float e   = expf(d + kActShift);
    const float sp  = log1pf(e);
    const float om  = expf(-kInterval * sp);
    const float alpha = 1.0f - om;

    float v = om;
    #pragma unroll
    for (int off = 1; off < 64; off <<= 1) {
        float o = __shfl_up(v, off, 64);
        if (lane >= off) v *= o;
    }
    if (lane == 63) s_wtot[wid] = v;
    __syncthreads();
    float wpref = 1.0f;
    #pragma unroll
    for (int w = 0; w < 4; ++w)
        if (w < wid) wpref *= s_wtot[w];
    const float total = s_wtot[0] * s_wtot[1] * s_wtot[2] * s_wtot[3];

    float excl = __shfl_up(v, 1, 64);
    if (lane == 0) excl = 1.0f;
    const float T  = wpref * excl;
    const float ws = T * alpha;

    out_w[(size_t)r * N_SAMP + s] = ws;

    float contrib[3];
    #pragma unroll
    for (int c = 0; c < 3; ++c) {
        const float* g = kgrid + (size_t)c * GRID_VOX;
        float k =
            g[o00 + z0] * w000 + g[o00 + z1] * w001 +
            g[o01 + z0] * w010 + g[o01 + z1] * w011 +
            g[o10 + z0] * w100 + g[o10 + z1] * w101 +
            g[o11 + z0] * w110 + g[o11 + z1] * w111;
        contrib[c] = ws * sigmoidf_(k);
    }

    #pragma unroll
    for (int c = 0; c < 3; ++c) {
        float x = contrib[c];
        #pragma unroll
        for (int off = 32; off >= 1; off >>= 1)
            x += __shfl_xor(x, off, 64);
        if (lane == 0) s_rgb[wid][c] = x;
    }
    __syncthreads();

    if (s == 0) {
        #pragma unroll
        for (int c = 0; c < 3; ++c) {
            float acc = s_rgb[0][c] + s_rgb[1][c] + s_rgb[2][c] + s_rgb[3][c];
            out_rgb[r * 3 + c] = acc + total;
        }
        out_ainv[r] = total;
    }
}

extern "C" void kernel_launch(void* const* d_in, const int* in_sizes, int n_in,
                              void* d_out, int out_size, void* d_ws, size_t ws_size,
                              hipStream_t stream) {
    const float* ray_pts = (const float*)d_in[0];
    const float* dgrid   = (const float*)d_in[1];
    const float* kgrid   = (const float*)d_in[2];

    float* out_rgb  = (float*)d_out;                       // 16384*3
    float* out_w    = out_rgb + (size_t)N_RAYS * 3;        // 16384*256
    float* out_ainv = out_w + (size_t)N_RAYS * N_SAMP;     // 16384

    const size_t bytes_per_copy = (size_t)COPY_VOX * 8;    // 32,768,000
    const size_t need4 = 4 * bytes_per_copy;               // 131 MB
    const size_t need2 = 2 * bytes_per_copy;               // 65.5 MB

    if (ws_size >= need4) {
        const int pairs = 4 * NBLK * 4;                    // 8,192,000
        repack_kernel<2><<<pairs / 256, 256, 0, stream>>>(dgrid, kgrid, (u32x4*)d_ws);
        render_blk_kernel<2><<<N_RAYS, N_SAMP, 0, stream>>>(
            ray_pts, (const float4*)d_ws, out_rgb, out_w, out_ainv);
    } else if (ws_size >= need2) {
        const int pairs = 2 * NBLK * 4;                    // 4,096,000
        repack_kernel<1><<<pairs / 256, 256, 0, stream>>>(dgrid, kgrid, (u32x4*)d_ws);
        render_blk_kernel<1><<<N_RAYS, N_SAMP, 0, stream>>>(
            ray_pts, (const float4*)d_ws, out_rgb, out_w, out_ainv);
    } else {
        render_kernel<<<N_RAYS, N_SAMP, 0, stream>>>(
            ray_pts, dgrid, kgrid, out_rgb, out_w, out_ainv);
    }
}

// Round 6
// 149.782 us; speedup vs baseline: 2.7488x; 1.1261x over previous
//
#include <hip/hip_runtime.h>

// Problem constants (from reference)
#define N_RAYS   16384
#define N_SAMP   256
#define GRID_N   160
#define GRID_VOX (GRID_N * GRID_N * GRID_N)   // 4,096,000
#define GB       80                            // 2x2x2 blocks per axis
#define NBLK     (GB * GB * GB)                // 512,000 blocks per copy
#define COPY_VOX (NBLK * 8)                    // 4,096,000 voxels per copy

typedef unsigned int u32x4 __attribute__((ext_vector_type(4)));

__device__ __constant__ float kXyzMin   = -1.2f;
__device__ __constant__ float kScale    = 159.0f / 2.4f;          // 66.25
__device__ __constant__ float kActShift = -9.21024036697530f;     // log(1/(1-1e-4)-1)
__device__ __constant__ float kInterval = 0.01f;

__device__ __forceinline__ float sigmoidf_(float x) {
    return 1.0f / (1.0f + expf(-x));
}

// f32 -> bf16 bits, round-nearest-even
__device__ __forceinline__ unsigned int f2bf(float f) {
    unsigned int u = __float_as_uint(f);
    return (u + 0x7fffu + ((u >> 16) & 1u)) >> 16;
}
__device__ __forceinline__ float bf_lo(unsigned int u) {
    return __uint_as_float(u << 16);
}
__device__ __forceinline__ float bf_hi(unsigned int u) {
    return __uint_as_float(u & 0xffff0000u);
}

// ---------------------------------------------------------------------------
// ONE-PASS repack for the 4-copy (y,z parity) tier.
// Output layout per copy (identical to render's expectation):
//   blk = (yb*80 + zb)*80 + xb  (x-fastest), pairidx = blk*4 + sx*2 + sy,
//   pair = 16B = voxels (z0,z1); copy c = py*2+pz at base c*NBLK*4.
// One thread owns (yb, xb, zb2, sx, sy) and produces the SAME pairidx for
// all 4 copies AND both z-blocks zb = 2*zb2, 2*zb2+1:
//   needs voxels x (1), y in {y0, y1=y0+1(clamped)}, z in [4*zb2, 4*zb2+4]
//   -> per (channel,row): one 16B-ALIGNED float4 + 1 guarded scalar.
// Source read ~1.1x (vs 4x), writes unchanged (8 x 16B NT full-line quads).
// ---------------------------------------------------------------------------
__global__ __launch_bounds__(256)
void repack4_kernel(const float* __restrict__ dgrid,
                    const float* __restrict__ kgrid,
                    u32x4* __restrict__ out)
{
    const int i = blockIdx.x * 256 + threadIdx.x;   // grid sized exactly
    const int p  = i & 3;
    const int sx = p >> 1, sy = p & 1;
    int t = i >> 2;
    const int zb2 = t % 40; t /= 40;                // z super-block (4 voxels)
    const int xb  = t % GB; const int yb = t / GB;

    const int x  = xb * 2 + sx;                     // <= 159
    const int y0 = yb * 2 + sy;                     // <= 159
    const int y1 = min(y0 + 1, GRID_N - 1);         // dup-clamp at edge
    const int za = zb2 * 4;                         // 16B-aligned float offset
    const bool zedge = (zb2 == 39);                 // za+4 == 160 would be OOB

    const int rowoff0 = (x * GRID_N + y0) * GRID_N + za;
    const int rowoff1 = (x * GRID_N + y1) * GRID_N + za;

    // v[dy][ch][zl], zl = 0..4  (z = za+zl)
    float v[2][4][5];
    #pragma unroll
    for (int dy = 0; dy < 2; ++dy) {
        const int ro = dy ? rowoff1 : rowoff0;
        #pragma unroll
        for (int c = 0; c < 4; ++c) {
            const float* plane = (c == 0) ? dgrid : kgrid + (size_t)(c - 1) * GRID_VOX;
            const float* rp = plane + ro;
            const float4 f = *(const float4*)rp;    // 16B aligned (ro % 4 == 0)
            v[dy][c][0] = f.x; v[dy][c][1] = f.y;
            v[dy][c][2] = f.z; v[dy][c][3] = f.w;
            v[dy][c][4] = zedge ? f.w : rp[4];      // z=159 dup at edge
        }
    }

    // pack voxels: lo = d | r<<16, hi = g | b<<16
    unsigned lo[2][5], hi[2][5];
    #pragma unroll
    for (int dy = 0; dy < 2; ++dy)
        #pragma unroll
        for (int zl = 0; zl < 5; ++zl) {
            lo[dy][zl] = f2bf(v[dy][0][zl]) | (f2bf(v[dy][1][zl]) << 16);
            hi[dy][zl] = f2bf(v[dy][2][zl]) | (f2bf(v[dy][3][zl]) << 16);
        }

    const int    blkE  = (yb * GB + zb2 * 2) * GB + xb;  // zb even block
    const size_t baseE = (size_t)blkE * 4 + p;
    const size_t baseO = baseE + (size_t)GB * 4;         // zb+1 -> +80 blocks

    // copy (py,pz): y-parity py selects row dy=py; z start = pz (+2 for odd zb)
    #pragma unroll
    for (int py = 0; py < 2; ++py)
        #pragma unroll
        for (int pz = 0; pz < 2; ++pz) {
            const size_t cbase = (size_t)(py * 2 + pz) * ((size_t)NBLK * 4);
            u32x4 a, b;
            a.x = lo[py][pz];     a.y = hi[py][pz];
            a.z = lo[py][pz + 1]; a.w = hi[py][pz + 1];
            b.x = lo[py][pz + 2]; b.y = hi[py][pz + 2];
            b.z = lo[py][pz + 3]; b.w = hi[py][pz + 3];
            __builtin_nontemporal_store(a, &out[cbase + baseE]);
            __builtin_nontemporal_store(b, &out[cbase + baseO]);
        }
}

// ---------------------------------------------------------------------------
// Two-copy repack (z parity only) — fallback tier, round-5 version.
// ---------------------------------------------------------------------------
__global__ __launch_bounds__(256)
void repack2_kernel(const float* __restrict__ dgrid,
                    const float* __restrict__ kgrid,
                    u32x4* __restrict__ out)
{
    const int i = blockIdx.x * 256 + threadIdx.x;   // grid sized exactly
    const int p  = i & 3;
    const int sx = p >> 1, sy = p & 1;
    int t = i >> 2;
    const int zb = t % GB; t /= GB;
    const int xb = t % GB; t /= GB;
    const int yb = t % GB; const int c = t / GB;    // c = pz in [0,2)
    const int pz = c;

    const int x  = xb * 2 + sx;
    const int y  = min(yb * 2 + sy, GRID_N - 1);
    const int zs = pz + zb * 2;
    const int z0 = min(zs,     GRID_N - 1);
    const int z1 = min(zs + 1, GRID_N - 1);

    const int g0 = (x * GRID_N + y) * GRID_N + z0;
    const int g1 = (x * GRID_N + y) * GRID_N + z1;

    const unsigned int d0  = f2bf(dgrid[g0]);
    const unsigned int r0  = f2bf(kgrid[g0]);
    const unsigned int gg0 = f2bf(kgrid[g0 + GRID_VOX]);
    const unsigned int b0  = f2bf(kgrid[g0 + 2 * GRID_VOX]);
    const unsigned int d1  = f2bf(dgrid[g1]);
    const unsigned int r1  = f2bf(kgrid[g1]);
    const unsigned int gg1 = f2bf(kgrid[g1 + GRID_VOX]);
    const unsigned int b1  = f2bf(kgrid[g1 + 2 * GRID_VOX]);

    u32x4 o;
    o.x = d0  | (r0 << 16);
    o.y = gg0 | (b0 << 16);
    o.z = d1  | (r1 << 16);
    o.w = gg1 | (b1 << 16);

    const size_t a = (size_t)c * ((size_t)NBLK * 4)
                   + (size_t)(((yb * GB + zb) * GB + xb) << 2) + p;
    __builtin_nontemporal_store(o, &out[a]);
}

// ---------------------------------------------------------------------------
// Render over the replicated block grid (x-fastest block order).
// YP==2: copy (y0&1, z0&1); the 4 needed float4s are contiguous [a0..a0+3].
// YP==1: copy (z0&1); 4 separate float4s (x,y straddle across blocks).
// ---------------------------------------------------------------------------
template<int YP>
__global__ __launch_bounds__(256)
void render_blk_kernel(const float* __restrict__ ray_pts,  // [N_RAYS, N_SAMP, 3]
                       const float4* __restrict__ P,       // packed copies
                       float* __restrict__ out_rgb,        // [N_RAYS, 3]
                       float* __restrict__ out_w,          // [N_RAYS, N_SAMP]
                       float* __restrict__ out_ainv)       // [N_RAYS]
{
    const int r    = blockIdx.x;
    const int s    = threadIdx.x;
    const int lane = s & 63;
    const int wid  = s >> 6;

    __shared__ float s_wtot[4];
    __shared__ float s_rgb[4][3];

    const float* rp = ray_pts + ((size_t)r * N_SAMP + s) * 3;
    const float px  = __builtin_nontemporal_load(&rp[0]);
    const float py_ = __builtin_nontemporal_load(&rp[1]);
    const float pz_ = __builtin_nontemporal_load(&rp[2]);

    float ux = fminf(fmaxf((px  - kXyzMin) * kScale, 0.0f), 159.0f);
    float uy = fminf(fmaxf((py_ - kXyzMin) * kScale, 0.0f), 159.0f);
    float uz = fminf(fmaxf((pz_ - kXyzMin) * kScale, 0.0f), 159.0f);
    int x0 = min((int)floorf(ux), GRID_N - 2);   // boundary: fx becomes 1.0
    int y0 = min((int)floorf(uy), GRID_N - 2);
    int z0 = min((int)floorf(uz), GRID_N - 2);
    const float fx = ux - (float)x0, fy = uy - (float)y0, fz = uz - (float)z0;
    const float gx = 1.0f - fx, gy = 1.0f - fy, gz = 1.0f - fz;

    const int zp = z0 & 1, zb = z0 >> 1;

    // q00=(x0,y0) q01=(x0,y1) q10=(x1,y0) q11=(x1,y1); each float4 = z-pair
    float4 q00, q01, q10, q11;
    if (YP == 2) {
        const int yp = y0 & 1, yb = y0 >> 1;
        const int xb = x0 >> 1, sx = x0 & 1;
        const float4* B = P + (size_t)(yp * 2 + zp) * (NBLK * 4);
        const int a0 = ((yb * GB + zb) * GB + xb) * 4 + sx * 2;
        // contiguous 64B: works for sx=0 (same block) and sx=1 (next block,
        // adjacent in x-fastest order; x0<=158 so xb+1<=79)
        q00 = B[a0];     q01 = B[a0 + 1];
        q10 = B[a0 + 2]; q11 = B[a0 + 3];
    } else {
        const int y1 = y0 + 1, x1 = x0 + 1;
        const float4* B = P + (size_t)zp * (NBLK * 4);
        #define ADDR(X, Y) \
            ((((Y >> 1) * GB + zb) * GB + (X >> 1)) * 4 + (X & 1) * 2 + (Y & 1))
        q00 = B[ADDR(x0, y0)]; q01 = B[ADDR(x0, y1)];
        q10 = B[ADDR(x1, y0)]; q11 = B[ADDR(x1, y1)];
        #undef ADDR
    }

    float d = 0.f, kr = 0.f, kg = 0.f, kb = 0.f;
    {
        // each float4: (.x,.y) = voxel at z0, (.z,.w) = voxel at z1
        const float wxy00 = gx * gy, wxy01 = gx * fy;
        const float wxy10 = fx * gy, wxy11 = fx * fy;
        #define ACC(Q, WXY)                                               \
        {                                                                 \
            const unsigned a0_ = __float_as_uint((Q).x);                  \
            const unsigned b0_ = __float_as_uint((Q).y);                  \
            const unsigned a1_ = __float_as_uint((Q).z);                  \
            const unsigned b1_ = __float_as_uint((Q).w);                  \
            const float w0_ = (WXY) * gz, w1_ = (WXY) * fz;               \
            d  += w0_ * bf_lo(a0_) + w1_ * bf_lo(a1_);                    \
            kr += w0_ * bf_hi(a0_) + w1_ * bf_hi(a1_);                    \
            kg += w0_ * bf_lo(b0_) + w1_ * bf_lo(b1_);                    \
            kb += w0_ * bf_hi(b0_) + w1_ * bf_hi(b1_);                    \
        }
        ACC(q00, wxy00); ACC(q01, wxy01); ACC(q10, wxy10); ACC(q11, wxy11);
        #undef ACC
    }

    // alpha = 1 - (1 + exp(d + shift))^(-interval)
    const float e     = expf(d + kActShift);
    const float sp    = log1pf(e);               // softplus; inf-safe
    const float om    = expf(-kInterval * sp);   // (1 - alpha)
    const float alpha = 1.0f - om;

    // exclusive cumprod of (1-alpha) across 256 samples
    float v = om;
    #pragma unroll
    for (int off = 1; off < 64; off <<= 1) {
        float o = __shfl_up(v, off, 64);
        if (lane >= off) v *= o;
    }
    if (lane == 63) s_wtot[wid] = v;
    __syncthreads();
    float wpref = 1.0f;
    #pragma unroll
    for (int w = 0; w < 4; ++w)
        if (w < wid) wpref *= s_wtot[w];
    const float total = s_wtot[0] * s_wtot[1] * s_wtot[2] * s_wtot[3];

    float excl = __shfl_up(v, 1, 64);
    if (lane == 0) excl = 1.0f;
    const float T  = wpref * excl;
    const float ws = T * alpha;

    __builtin_nontemporal_store(ws, &out_w[(size_t)r * N_SAMP + s]);

    float contrib[3];
    contrib[0] = ws * sigmoidf_(kr);
    contrib[1] = ws * sigmoidf_(kg);
    contrib[2] = ws * sigmoidf_(kb);

    #pragma unroll
    for (int c = 0; c < 3; ++c) {
        float x = contrib[c];
        #pragma unroll
        for (int off = 32; off >= 1; off >>= 1)
            x += __shfl_xor(x, off, 64);
        if (lane == 0) s_rgb[wid][c] = x;
    }
    __syncthreads();

    if (s == 0) {
        #pragma unroll
        for (int c = 0; c < 3; ++c) {
            float acc = s_rgb[0][c] + s_rgb[1][c] + s_rgb[2][c] + s_rgb[3][c];
            out_rgb[r * 3 + c] = acc + total;   // + alphainv_last
        }
        out_ainv[r] = total;
    }
}

// ---------------------------------------------------------------------------
// Last-resort fallback (round-1 planar kernel) if ws is tiny.
// ---------------------------------------------------------------------------
__global__ __launch_bounds__(256)
void render_kernel(const float* __restrict__ ray_pts,
                   const float* __restrict__ dgrid,
                   const float* __restrict__ kgrid,
                   float* __restrict__ out_rgb,
                   float* __restrict__ out_w,
                   float* __restrict__ out_ainv)
{
    const int r    = blockIdx.x;
    const int s    = threadIdx.x;
    const int lane = s & 63;
    const int wid  = s >> 6;

    __shared__ float s_wtot[4];
    __shared__ float s_rgb[4][3];

    const float* rp = ray_pts + ((size_t)r * N_SAMP + s) * 3;
    const float px = rp[0], py = rp[1], pz = rp[2];

    float ux = fminf(fmaxf((px - kXyzMin) * kScale, 0.0f), 159.0f);
    float uy = fminf(fmaxf((py - kXyzMin) * kScale, 0.0f), 159.0f);
    float uz = fminf(fmaxf((pz - kXyzMin) * kScale, 0.0f), 159.0f);
    int x0 = (int)floorf(ux), y0 = (int)floorf(uy), z0 = (int)floorf(uz);
    int x1 = min(x0 + 1, 159), y1 = min(y0 + 1, 159), z1 = min(z0 + 1, 159);
    float fx = ux - (float)x0, fy = uy - (float)y0, fz = uz - (float)z0;
    float gx = 1.0f - fx, gy = 1.0f - fy, gz = 1.0f - fz;

    const int o00 = (x0 * GRID_N + y0) * GRID_N;
    const int o01 = (x0 * GRID_N + y1) * GRID_N;
    const int o10 = (x1 * GRID_N + y0) * GRID_N;
    const int o11 = (x1 * GRID_N + y1) * GRID_N;

    const float w000 = gx * gy * gz, w001 = gx * gy * fz;
    const float w010 = gx * fy * gz, w011 = gx * fy * fz;
    const float w100 = fx * gy * gz, w101 = fx * gy * fz;
    const float w110 = fx * fy * gz, w111 = fx * fy * fz;

    float d =
        dgrid[o00 + z0] * w000 + dgrid[o00 + z1] * w001 +
        dgrid[o01 + z0] * w010 + dgrid[o01 + z1] * w011 +
        dgrid[o10 + z0] * w100 + dgrid[o10 + z1] * w101 +
        dgrid[o11 + z0] * w110 + dgrid[o11 + z1] * w111;

    const float e   = expf(d + kActShift);
    const float sp  = log1pf(e);
    const float om  = expf(-kInterval * sp);
    const float alpha = 1.0f - om;

    float v = om;
    #pragma unroll
    for (int off = 1; off < 64; off <<= 1) {
        float o = __shfl_up(v, off, 64);
        if (lane >= off) v *= o;
    }
    if (lane == 63) s_wtot[wid] = v;
    __syncthreads();
    float wpref = 1.0f;
    #pragma unroll
    for (int w = 0; w < 4; ++w)
        if (w < wid) wpref *= s_wtot[w];
    const float total = s_wtot[0] * s_wtot[1] * s_wtot[2] * s_wtot[3];

    float excl = __shfl_up(v, 1, 64);
    if (lane == 0) excl = 1.0f;
    const float T  = wpref * excl;
    const float ws = T * alpha;

    out_w[(size_t)r * N_SAMP + s] = ws;

    float contrib[3];
    #pragma unroll
    for (int c = 0; c < 3; ++c) {
        const float* g = kgrid + (size_t)c * GRID_VOX;
        float k =
            g[o00 + z0] * w000 + g[o00 + z1] * w001 +
            g[o01 + z0] * w010 + g[o01 + z1] * w011 +
            g[o10 + z0] * w100 + g[o10 + z1] * w101 +
            g[o11 + z0] * w110 + g[o11 + z1] * w111;
        contrib[c] = ws * sigmoidf_(k);
    }

    #pragma unroll
    for (int c = 0; c < 3; ++c) {
        float x = contrib[c];
        #pragma unroll
        for (int off = 32; off >= 1; off >>= 1)
            x += __shfl_xor(x, off, 64);
        if (lane == 0) s_rgb[wid][c] = x;
    }
    __syncthreads();

    if (s == 0) {
        #pragma unroll
        for (int c = 0; c < 3; ++c) {
            float acc = s_rgb[0][c] + s_rgb[1][c] + s_rgb[2][c] + s_rgb[3][c];
            out_rgb[r * 3 + c] = acc + total;
        }
        out_ainv[r] = total;
    }
}

extern "C" void kernel_launch(void* const* d_in, const int* in_sizes, int n_in,
                              void* d_out, int out_size, void* d_ws, size_t ws_size,
                              hipStream_t stream) {
    const float* ray_pts = (const float*)d_in[0];
    const float* dgrid   = (const float*)d_in[1];
    const float* kgrid   = (const float*)d_in[2];

    float* out_rgb  = (float*)d_out;                       // 16384*3
    float* out_w    = out_rgb + (size_t)N_RAYS * 3;        // 16384*256
    float* out_ainv = out_w + (size_t)N_RAYS * N_SAMP;     // 16384

    const size_t bytes_per_copy = (size_t)COPY_VOX * 8;    // 32,768,000
    const size_t need4 = 4 * bytes_per_copy;               // 131 MB
    const size_t need2 = 2 * bytes_per_copy;               // 65.5 MB

    if (ws_size >= need4) {
        // one-pass repack: threads = yb(80) * xb(80) * zb2(40) * p(4)
        const int threads = 80 * 80 * 40 * 4;              // 1,024,000
        repack4_kernel<<<threads / 256, 256, 0, stream>>>(dgrid, kgrid, (u32x4*)d_ws);
        render_blk_kernel<2><<<N_RAYS, N_SAMP, 0, stream>>>(
            ray_pts, (const float4*)d_ws, out_rgb, out_w, out_ainv);
    } else if (ws_size >= need2) {
        const int pairs = 2 * NBLK * 4;                    // 4,096,000
        repack2_kernel<<<pairs / 256, 256, 0, stream>>>(dgrid, kgrid, (u32x4*)d_ws);
        render_blk_kernel<1><<<N_RAYS, N_SAMP, 0, stream>>>(
            ray_pts, (const float4*)d_ws, out_rgb, out_w, out_ainv);
    } else {
        render_kernel<<<N_RAYS, N_SAMP, 0, stream>>>(
            ray_pts, dgrid, kgrid, out_rgb, out_w, out_ainv);
    }
}